// Round 1
// baseline (560.481 us; speedup 1.0000x reference)
//
#include <hip/hip_runtime.h>

#define LOG2E 1.4426950408889634f
#define LN2   0.6931471805599453f

// One wave (64 lanes) per batch element. Lane i owns state i.
// Recurrence in exp domain: score'[i] = emit[i] + a + ln( sum_j M[i,j] * exp(score[j]-a) )
// with M[i,j] = exp(trans[i,j]) held in 64 VGPRs per lane (row i), a = lane-0 anchor.
__global__ __launch_bounds__(64, 1) void crf_fwd_33852932227637(
    const float* __restrict__ h,
    const float* __restrict__ trans,
    const int* __restrict__ lengths,
    float* __restrict__ out,
    int T) {
  constexpr int N = 64;
  const int b = blockIdx.x;
  const int lane = threadIdx.x;

  __shared__ __align__(16) float vbuf[N];
  const float4* vv = (const float4*)vbuf;

  const float* hb = h + (size_t)b * T * N;

  // M row for this lane: M[lane][j] = exp(trans[lane*64+j])  (64 VGPRs)
  float Mrow[N];
  const float4* trow = (const float4*)(trans + lane * N);
#pragma unroll
  for (int q = 0; q < 16; ++q) {
    float4 tq = trow[q];
    Mrow[4 * q + 0] = __builtin_amdgcn_exp2f(tq.x * LOG2E);
    Mrow[4 * q + 1] = __builtin_amdgcn_exp2f(tq.y * LOG2E);
    Mrow[4 * q + 2] = __builtin_amdgcn_exp2f(tq.z * LOG2E);
    Mrow[4 * q + 3] = __builtin_amdgcn_exp2f(tq.w * LOG2E);
  }

  const int len = lengths[b];

  // Step t=0 in closed form: init is NEG_INF everywhere except START (N-2) = 0,
  // and exp(-10000 + x) == 0 in fp32, so score[i] = h[b,0,i] + trans[i, N-2].
  float score = hb[lane] + trans[lane * N + (N - 2)];

  auto step = [&](float emit) {
    float anchor =
        __uint_as_float(__builtin_amdgcn_readfirstlane(__float_as_uint(score)));
    float v = __builtin_amdgcn_exp2f((score - anchor) * LOG2E);
    __syncthreads();
    vbuf[lane] = v;
    __syncthreads();
    float a0 = 0, a1 = 0, a2 = 0, a3 = 0, a4 = 0, a5 = 0, a6 = 0, a7 = 0;
#pragma unroll
    for (int q = 0; q < 8; ++q) {
      float4 x = vv[2 * q];
      float4 y = vv[2 * q + 1];
      a0 = fmaf(Mrow[8 * q + 0], x.x, a0);
      a1 = fmaf(Mrow[8 * q + 1], x.y, a1);
      a2 = fmaf(Mrow[8 * q + 2], x.z, a2);
      a3 = fmaf(Mrow[8 * q + 3], x.w, a3);
      a4 = fmaf(Mrow[8 * q + 4], y.x, a4);
      a5 = fmaf(Mrow[8 * q + 5], y.y, a5);
      a6 = fmaf(Mrow[8 * q + 6], y.z, a6);
      a7 = fmaf(Mrow[8 * q + 7], y.w, a7);
    }
    float s = ((a0 + a1) + (a2 + a3)) + ((a4 + a5) + (a6 + a7));
    score = emit + anchor + LN2 * __builtin_amdgcn_logf(s);
  };

  // Software-pipelined emissions, 8 deep, static register slots.
  float eb[8];
#pragma unroll
  for (int u = 0; u < 8; ++u) {
    int t0 = 1 + u;
    int tc = t0 < T ? t0 : T - 1;
    eb[u] = hb[(size_t)tc * N + lane];
  }

  int t = 1;
  for (; t + 8 <= len; t += 8) {
#pragma unroll
    for (int u = 0; u < 8; ++u) {
      step(eb[u]);
      int tn = t + u + 8;
      int tc = tn < T ? tn : T - 1;  // stay in-bounds; value unused past len
      eb[u] = hb[(size_t)tc * N + lane];
    }
  }
  for (; t < len; ++t) {  // <=7 tail steps, direct loads
    step(hb[(size_t)t * N + lane]);
  }

  // Terminal transition to END (N-1), then wave-wide logsumexp over states.
  float fin = score + trans[(N - 1) * N + lane];
  float m = fin;
#pragma unroll
  for (int off = 32; off >= 1; off >>= 1)
    m = fmaxf(m, __shfl_xor(m, off, 64));
  float z = __builtin_amdgcn_exp2f((fin - m) * LOG2E);
#pragma unroll
  for (int off = 32; off >= 1; off >>= 1)
    z += __shfl_xor(z, off, 64);
  if (lane == 0) out[b] = m + LN2 * __builtin_amdgcn_logf(z);
}

extern "C" void kernel_launch(void* const* d_in, const int* in_sizes, int n_in,
                              void* d_out, int out_size, void* d_ws, size_t ws_size,
                              hipStream_t stream) {
  const float* h = (const float*)d_in[0];
  const float* trans = (const float*)d_in[1];
  const int* lengths = (const int*)d_in[2];
  float* out = (float*)d_out;
  const int B = in_sizes[2];
  const int N = 64;
  const int T = in_sizes[0] / (B * N);
  crf_fwd_33852932227637<<<B, 64, 0, stream>>>(h, trans, lengths, out, T);
}

// Round 2
// 541.162 us; speedup vs baseline: 1.0357x; 1.0357x over previous
//
#include <hip/hip_runtime.h>

#define LOG2E 1.4426950408889634f
#define LN2   0.6931471805599453f

// One wave (64 lanes) per batch element. Lane i owns state i.
// Recurrence in exp domain: score'[i] = emit[i] + a + ln( sum_j M[i,j] * exp(score[j]-a) )
// with M[i,j] = exp(trans[i,j]) held in 64 VGPRs per lane (row i), a = lane-0 anchor.
//
// Block == 1 wave, so NO s_barrier is used: DS ops from one wave execute in
// order in the LDS pipe (wave-synchronous LDS idiom); wave_barrier() only
// stops compiler reordering and emits no instruction — this keeps the
// prefetched emission loads in flight (no vmcnt(0) drain per step).
__global__ __launch_bounds__(64, 1) void crf_fwd_33852932227637(
    const float* __restrict__ h,
    const float* __restrict__ trans,
    const int* __restrict__ lengths,
    float* __restrict__ out,
    int T) {
  constexpr int N = 64;
  const int b = blockIdx.x;
  const int lane = threadIdx.x;

  __shared__ __align__(16) float vbuf[N];
  const float4* vv = (const float4*)vbuf;

  const float* hb = h + (size_t)b * T * N;

  // M row for this lane: M[lane][j] = exp(trans[lane*64+j])  (64 VGPRs)
  float Mrow[N];
  const float4* trow = (const float4*)(trans + lane * N);
#pragma unroll
  for (int q = 0; q < 16; ++q) {
    float4 tq = trow[q];
    Mrow[4 * q + 0] = __builtin_amdgcn_exp2f(tq.x * LOG2E);
    Mrow[4 * q + 1] = __builtin_amdgcn_exp2f(tq.y * LOG2E);
    Mrow[4 * q + 2] = __builtin_amdgcn_exp2f(tq.z * LOG2E);
    Mrow[4 * q + 3] = __builtin_amdgcn_exp2f(tq.w * LOG2E);
  }

  const int len = lengths[b];

  // Step t=0 in closed form: init is NEG_INF everywhere except START (N-2) = 0,
  // and exp(-10000 + x) == 0 in fp32, so score[i] = h[b,0,i] + trans[i, N-2].
  float score = hb[lane] + trans[lane * N + (N - 2)];

  auto step = [&](float emit) {
    float anchor =
        __uint_as_float(__builtin_amdgcn_readfirstlane(__float_as_uint(score)));
    float v = __builtin_amdgcn_exp2f((score - anchor) * LOG2E);
    __builtin_amdgcn_wave_barrier();  // prior reads complete before overwrite
    vbuf[lane] = v;
    __builtin_amdgcn_wave_barrier();  // write issued before this step's reads
    float a0 = 0, a1 = 0, a2 = 0, a3 = 0, a4 = 0, a5 = 0, a6 = 0, a7 = 0;
#pragma unroll
    for (int q = 0; q < 8; ++q) {
      float4 x = vv[2 * q];
      float4 y = vv[2 * q + 1];
      a0 = fmaf(Mrow[8 * q + 0], x.x, a0);
      a1 = fmaf(Mrow[8 * q + 1], x.y, a1);
      a2 = fmaf(Mrow[8 * q + 2], x.z, a2);
      a3 = fmaf(Mrow[8 * q + 3], x.w, a3);
      a4 = fmaf(Mrow[8 * q + 4], y.x, a4);
      a5 = fmaf(Mrow[8 * q + 5], y.y, a5);
      a6 = fmaf(Mrow[8 * q + 6], y.z, a6);
      a7 = fmaf(Mrow[8 * q + 7], y.w, a7);
    }
    float s = ((a0 + a1) + (a2 + a3)) + ((a4 + a5) + (a6 + a7));
    score = emit + anchor + LN2 * __builtin_amdgcn_logf(s);
  };

  // Software-pipelined emissions, 8 deep, static register slots.
  float eb[8];
#pragma unroll
  for (int u = 0; u < 8; ++u) {
    int t0 = 1 + u;
    int tc = t0 < T ? t0 : T - 1;
    eb[u] = hb[(size_t)tc * N + lane];
  }

  int t = 1;
  for (; t + 8 <= len; t += 8) {
#pragma unroll
    for (int u = 0; u < 8; ++u) {
      step(eb[u]);
      int tn = t + u + 8;
      int tc = tn < T ? tn : T - 1;  // stay in-bounds; value unused past len
      eb[u] = hb[(size_t)tc * N + lane];
    }
  }
  for (; t < len; ++t) {  // <=7 tail steps, direct loads
    step(hb[(size_t)t * N + lane]);
  }

  // Terminal transition to END (N-1), then wave-wide logsumexp over states.
  float fin = score + trans[(N - 1) * N + lane];
  float m = fin;
#pragma unroll
  for (int off = 32; off >= 1; off >>= 1)
    m = fmaxf(m, __shfl_xor(m, off, 64));
  float z = __builtin_amdgcn_exp2f((fin - m) * LOG2E);
#pragma unroll
  for (int off = 32; off >= 1; off >>= 1)
    z += __shfl_xor(z, off, 64);
  if (lane == 0) out[b] = m + LN2 * __builtin_amdgcn_logf(z);
}

extern "C" void kernel_launch(void* const* d_in, const int* in_sizes, int n_in,
                              void* d_out, int out_size, void* d_ws, size_t ws_size,
                              hipStream_t stream) {
  const float* h = (const float*)d_in[0];
  const float* trans = (const float*)d_in[1];
  const int* lengths = (const int*)d_in[2];
  float* out = (float*)d_out;
  const int B = in_sizes[2];
  const int N = 64;
  const int T = in_sizes[0] / (B * N);
  crf_fwd_33852932227637<<<B, 64, 0, stream>>>(h, trans, lengths, out, T);
}

// Round 3
// 408.066 us; speedup vs baseline: 1.3735x; 1.3262x over previous
//
#include <hip/hip_runtime.h>

#define LOG2E 1.4426950408889634f
#define LN2   0.6931471805599453f

// One wave (64 lanes) per batch element. Lane i owns state i.
// Recurrence kept in log2 domain:
//   score2'[i] = emit2[i] + a2 + log2( sum_j M[i,j] * 2^(score2[j]-a2) )
// with M[i,j] = 2^(trans[i,j]*log2e) = exp(trans[i,j]) in 64 VGPRs (row i),
// emit2 = emit*log2e, a2 = lane-0 anchor (spread across states is bounded by
// emit+trans-row ranges ~ +-20, so 2^(d) never overflows fp32).
//
// Cross-lane broadcast is done with v_readlane (VALU->SGPR, ~few cycles,
// independent ops) instead of an LDS write->read round trip (~240+ cycles of
// serial DS-pipe latency, which round-2 counters showed dominated the step).
__device__ __forceinline__ float bcast(float v, int l) {
  return __uint_as_float(__builtin_amdgcn_readlane(__float_as_uint(v), l));
}

__global__ __launch_bounds__(64, 1) void crf_fwd_33852932227637(
    const float* __restrict__ h,
    const float* __restrict__ trans,
    const int* __restrict__ lengths,
    float* __restrict__ out,
    int T) {
  constexpr int N = 64;
  const int b = blockIdx.x;
  const int lane = threadIdx.x;

  const float* hb = h + (size_t)b * T * N;

  // M row for this lane: M[lane][j] = exp(trans[lane*64+j])  (64 VGPRs)
  float Mrow[N];
  const float4* trow = (const float4*)(trans + lane * N);
#pragma unroll
  for (int q = 0; q < 16; ++q) {
    float4 tq = trow[q];
    Mrow[4 * q + 0] = __builtin_amdgcn_exp2f(tq.x * LOG2E);
    Mrow[4 * q + 1] = __builtin_amdgcn_exp2f(tq.y * LOG2E);
    Mrow[4 * q + 2] = __builtin_amdgcn_exp2f(tq.z * LOG2E);
    Mrow[4 * q + 3] = __builtin_amdgcn_exp2f(tq.w * LOG2E);
  }

  const int len = lengths[b];

  // Step t=0 closed form (exp(-10000+x)==0 in fp32): score[i]=h[b,0,i]+trans[i,START]
  float score2 = (hb[lane] + trans[lane * N + (N - 2)]) * LOG2E;

  auto step = [&](float emit2) {
    float a2 = __uint_as_float(
        __builtin_amdgcn_readfirstlane(__float_as_uint(score2)));
    float w = __builtin_amdgcn_exp2f(score2 - a2);
    float acc[8];
#pragma unroll
    for (int k = 0; k < 8; ++k) acc[k] = 0.0f;
#pragma unroll
    for (int j = 0; j < N; ++j) {
      acc[j & 7] = fmaf(Mrow[j], bcast(w, j), acc[j & 7]);
    }
    float s = ((acc[0] + acc[1]) + (acc[2] + acc[3])) +
              ((acc[4] + acc[5]) + (acc[6] + acc[7]));
    score2 = emit2 + a2 + __builtin_amdgcn_logf(s);  // v_log_f32 = log2
  };

  // Software-pipelined emissions (pre-scaled by log2e), 8 deep.
  float eb[8];
#pragma unroll
  for (int u = 0; u < 8; ++u) {
    int t0 = 1 + u;
    int tc = t0 < T ? t0 : T - 1;
    eb[u] = hb[(size_t)tc * N + lane] * LOG2E;
  }

  int t = 1;
  for (; t + 8 <= len; t += 8) {
#pragma unroll
    for (int u = 0; u < 8; ++u) {
      step(eb[u]);
      int tn = t + u + 8;
      int tc = tn < T ? tn : T - 1;  // in-bounds; value unused past len
      eb[u] = hb[(size_t)tc * N + lane] * LOG2E;
    }
  }
  for (; t < len; ++t) {  // <=7 tail steps
    step(hb[(size_t)t * N + lane] * LOG2E);
  }

  // Terminal transition to END (N-1), then wave-wide logsumexp (natural log out).
  float fin = score2 * LN2 + trans[(N - 1) * N + lane];
  float m = fin;
#pragma unroll
  for (int off = 32; off >= 1; off >>= 1)
    m = fmaxf(m, __shfl_xor(m, off, 64));
  float z = __builtin_amdgcn_exp2f((fin - m) * LOG2E);
#pragma unroll
  for (int off = 32; off >= 1; off >>= 1)
    z += __shfl_xor(z, off, 64);
  if (lane == 0) out[b] = m + LN2 * __builtin_amdgcn_logf(z);
}

extern "C" void kernel_launch(void* const* d_in, const int* in_sizes, int n_in,
                              void* d_out, int out_size, void* d_ws, size_t ws_size,
                              hipStream_t stream) {
  const float* h = (const float*)d_in[0];
  const float* trans = (const float*)d_in[1];
  const int* lengths = (const int*)d_in[2];
  float* out = (float*)d_out;
  const int B = in_sizes[2];
  const int N = 64;
  const int T = in_sizes[0] / (B * N);
  crf_fwd_33852932227637<<<B, 64, 0, stream>>>(h, trans, lengths, out, T);
}